// Round 1
// baseline (264.240 us; speedup 1.0000x reference)
//
#include <hip/hip_runtime.h>
#include <hip/hip_bf16.h>
#include <cstdint>

#define S_LEN 4096
#define D_DIM 512
#define NWIN  511
#define KDIM  8192
#define BM    64
#define THREADS 512

typedef __attribute__((ext_vector_type(8))) short short8;
typedef __attribute__((ext_vector_type(4))) float f32x4;

__device__ __forceinline__ unsigned short f2b(float f) {
    union { float f; unsigned int u; } v; v.f = f;
    unsigned int r = v.u + 0x7FFFu + ((v.u >> 16) & 1u);
    return (unsigned short)(r >> 16);
}

// W [8192][512] fp32  ->  Wt [512][8192] bf16 (transposed, linear layout)
__global__ void wcvt_kernel(const float* __restrict__ W, unsigned short* __restrict__ Wt) {
    __shared__ unsigned short tile[64][65];
    int k0 = (blockIdx.x >> 3) << 6;
    int d0 = (blockIdx.x & 7) << 6;
    int tid = threadIdx.x;
    int c = tid & 63, r4 = tid >> 6;
#pragma unroll
    for (int rr = 0; rr < 16; ++rr) {
        int r = rr * 4 + r4;
        tile[r][c] = f2b(W[(size_t)(k0 + r) * D_DIM + d0 + c]);
    }
    __syncthreads();
#pragma unroll
    for (int rr = 0; rr < 16; ++rr) {
        int dd = rr * 4 + r4;
        Wt[(size_t)(d0 + dd) * KDIM + k0 + c] = tile[c][dd];
    }
}

// Fused windows-GEMM + bias + exact GELU + LayerNorm.
// Block: batch b, windows [n0, n0+64). 8 waves; wave w owns cols [64w, 64w+64).
template<bool USE_WS>
__global__ __launch_bounds__(THREADS, 2)
void fused_kernel(const float* __restrict__ x,
                  const unsigned short* __restrict__ Wt,
                  const float* __restrict__ Wf,
                  const float* __restrict__ bias,
                  const float* __restrict__ gamma,
                  const float* __restrict__ beta,
                  float* __restrict__ out)
{
    __shared__ unsigned short lsA[BM * 64];     // [win][k/8 swizzled]  8 KB
    __shared__ unsigned short lsB[D_DIM * 64];  // [d][k/8 swizzled]   64 KB
    __shared__ float redS[8][64];
    __shared__ float redQ[8][64];

    const int blk = blockIdx.x;
    const int b  = blk >> 3;
    const int n0 = (blk & 7) << 6;
    const int tid = threadIdx.x;
    const int lane = tid & 63;
    const int wid  = tid >> 6;
    const int r15 = lane & 15, hi = lane >> 4;
    const float* xb = x + (size_t)b * S_LEN * D_DIM;

    f32x4 acc[4][4] = {};

    for (int s = 0; s < 128; ++s) {
        const int c0 = (s >> 4) << 6;
        const int tt = s & 15;
        const int t  = (tt >> 1) | ((tt & 1) << 3);   // 0,8,1,9,... so row reuse is 1 step apart

        // ---- stage B tile: Wt rows d, k-slice [t*512+c0, +64), swizzled source ----
        if constexpr (USE_WS) {
#pragma unroll
            for (int j = 0; j < 8; ++j) {
                int slot = wid * 512 + j * 64 + lane;
                int d = slot >> 3, kb = slot & 7;
                const unsigned short* src = Wt + (size_t)d * KDIM + t * D_DIM + c0 + ((kb ^ (d & 7)) << 3);
                __builtin_amdgcn_global_load_lds(
                    (const __attribute__((address_space(1))) void*)src,
                    (__attribute__((address_space(3))) void*)(&lsB[slot * 8]),
                    16, 0, 0);
            }
        } else {
            // correctness fallback (ws too small): scalar gather from fp32 W
#pragma unroll
            for (int j = 0; j < 8; ++j) {
                int slot = tid + j * 512;
                int d = slot >> 3, kb = slot & 7;
                int kbase = t * D_DIM + c0 + ((kb ^ (d & 7)) << 3);
                short8 u;
#pragma unroll
                for (int e = 0; e < 8; ++e)
                    u[e] = (short)f2b(Wf[(size_t)(kbase + e) * D_DIM + d]);
                *(short8*)&lsB[slot * 8] = u;
            }
        }

        // ---- stage A tile: 64 windows x 64 k (fp32 -> bf16), swizzled ds_write ----
        {
            int i = tid >> 3, k8 = tid & 7;
            int row = 8 * (n0 + i) + t;
            if (row > S_LEN - 1) row = S_LEN - 1;     // clamp for invalid window 511
            const float* src = xb + (size_t)row * D_DIM + c0 + k8 * 8;
            float4 f0 = *(const float4*)src;
            float4 f1 = *(const float4*)(src + 4);
            short8 u;
            u[0] = (short)f2b(f0.x); u[1] = (short)f2b(f0.y);
            u[2] = (short)f2b(f0.z); u[3] = (short)f2b(f0.w);
            u[4] = (short)f2b(f1.x); u[5] = (short)f2b(f1.y);
            u[6] = (short)f2b(f1.z); u[7] = (short)f2b(f1.w);
            int kb = k8 ^ (i & 7);
            *(short8*)&lsA[i * 64 + kb * 8] = u;
        }
        __syncthreads();

        // ---- fragments + MFMA ----
        short8 afr[4][2], bfr[4][2];
#pragma unroll
        for (int m = 0; m < 4; ++m) {
            int row = 16 * m + r15;
#pragma unroll
            for (int k32 = 0; k32 < 2; ++k32) {
                int kb = (k32 * 4 + hi) ^ (row & 7);
                afr[m][k32] = *(const short8*)&lsA[row * 64 + kb * 8];
            }
        }
#pragma unroll
        for (int n = 0; n < 4; ++n) {
            int col = (wid << 6) + 16 * n + r15;
#pragma unroll
            for (int k32 = 0; k32 < 2; ++k32) {
                int kb = (k32 * 4 + hi) ^ (col & 7);
                bfr[n][k32] = *(const short8*)&lsB[col * 64 + kb * 8];
            }
        }
#pragma unroll
        for (int k32 = 0; k32 < 2; ++k32)
#pragma unroll
            for (int m = 0; m < 4; ++m)
#pragma unroll
                for (int n = 0; n < 4; ++n)
                    acc[m][n] = __builtin_amdgcn_mfma_f32_16x16x32_bf16(
                        afr[m][k32], bfr[n][k32], acc[m][n], 0, 0, 0);
        __syncthreads();
    }

    // ---- epilogue: bias + exact GELU + LayerNorm ----
    float bias4[4], gam4[4], bet4[4];
#pragma unroll
    for (int n = 0; n < 4; ++n) {
        int d = (wid << 6) + 16 * n + r15;
        bias4[n] = bias[d]; gam4[n] = gamma[d]; bet4[n] = beta[d];
    }
    float sum_[4][4], sq_[4][4];   // [m][reg]
#pragma unroll
    for (int m = 0; m < 4; ++m)
#pragma unroll
        for (int r = 0; r < 4; ++r) { sum_[m][r] = 0.f; sq_[m][r] = 0.f; }
#pragma unroll
    for (int m = 0; m < 4; ++m)
#pragma unroll
        for (int n = 0; n < 4; ++n)
#pragma unroll
            for (int r = 0; r < 4; ++r) {
                float h = acc[m][n][r] + bias4[n];
                float g = 0.5f * h * (1.0f + erff(h * 0.70710678118654752f));
                acc[m][n][r] = g;
                sum_[m][r] += g;
                sq_[m][r]  += g * g;
            }
    // reduce 64 cols of a row: 4 in-lane (done) + 16 lanes of the r15 group
#pragma unroll
    for (int m = 0; m < 4; ++m)
#pragma unroll
        for (int r = 0; r < 4; ++r) {
            float sv = sum_[m][r], qv = sq_[m][r];
#pragma unroll
            for (int msk = 1; msk < 16; msk <<= 1) {
                sv += __shfl_xor(sv, msk, 64);
                qv += __shfl_xor(qv, msk, 64);
            }
            sum_[m][r] = sv; sq_[m][r] = qv;
        }
    if (r15 == 0) {
#pragma unroll
        for (int m = 0; m < 4; ++m)
#pragma unroll
            for (int r = 0; r < 4; ++r) {
                int row16 = 16 * m + hi * 4 + r;
                redS[wid][row16] = sum_[m][r];
                redQ[wid][row16] = sq_[m][r];
            }
    }
    __syncthreads();
#pragma unroll
    for (int m = 0; m < 4; ++m) {
#pragma unroll
        for (int r = 0; r < 4; ++r) {
            int row16 = 16 * m + hi * 4 + r;
            float sv = 0.f, qv = 0.f;
#pragma unroll
            for (int w = 0; w < 8; ++w) { sv += redS[w][row16]; qv += redQ[w][row16]; }
            float mu  = sv * (1.0f / 512.0f);
            float var = qv * (1.0f / 512.0f) - mu * mu;
            float inv = rsqrtf(var + 1e-5f);
            int win = n0 + row16;
            if (win < NWIN) {
                size_t obase = ((size_t)b * NWIN + win) * D_DIM;
#pragma unroll
                for (int n = 0; n < 4; ++n) {
                    int d = (wid << 6) + 16 * n + r15;
                    out[obase + d] = (acc[m][n][r] - mu) * inv * gam4[n] + bet4[n];
                }
            }
        }
    }
}

extern "C" void kernel_launch(void* const* d_in, const int* in_sizes, int n_in,
                              void* d_out, int out_size, void* d_ws, size_t ws_size,
                              hipStream_t stream) {
    const float* x     = (const float*)d_in[0];
    const float* W     = (const float*)d_in[1];
    const float* bias  = (const float*)d_in[2];
    const float* gamma = (const float*)d_in[3];
    const float* beta  = (const float*)d_in[4];
    float* out = (float*)d_out;

    const size_t wt_bytes = (size_t)D_DIM * KDIM * sizeof(unsigned short);
    if (ws_size >= wt_bytes) {
        unsigned short* Wt = (unsigned short*)d_ws;
        wcvt_kernel<<<1024, 256, 0, stream>>>(W, Wt);
        fused_kernel<true><<<256, THREADS, 0, stream>>>(x, Wt, W, bias, gamma, beta, out);
    } else {
        fused_kernel<false><<<256, THREADS, 0, stream>>>(x, nullptr, W, bias, gamma, beta, out);
    }
}

// Round 2
// 218.253 us; speedup vs baseline: 1.2107x; 1.2107x over previous
//
#include <hip/hip_runtime.h>
#include <hip/hip_bf16.h>
#include <cstdint>

#define S_LEN 4096
#define D_DIM 512
#define NWIN  511
#define KDIM  8192
#define THREADS 512

typedef __attribute__((ext_vector_type(8))) short short8;
typedef __attribute__((ext_vector_type(4))) float f32x4;

__device__ __forceinline__ unsigned short f2b(float f) {
    union { float f; unsigned int u; } v; v.f = f;
    unsigned int r = v.u + 0x7FFFu + ((v.u >> 16) & 1u);
    return (unsigned short)(r >> 16);
}

// ---------------------------------------------------------------------------
// Pre-pass: pack W [8192][512] fp32 into bf16 MFMA-fragment order.
// For K-step s (t=s>>3, c0=(s&7)*64), wave w, frag f=(n*2+k32), lane l, elem e:
//   value = W[t*512 + c0 + k32*32 + (l>>4)*8 + e][64w + 16n + (l&15)]
//   at short8 slot ((s*8+w)*8 + f)*64 + l.
// Mapping is bit-identical to R1's lsB staging+read path (verified pass).
// ---------------------------------------------------------------------------
__global__ void wpack_kernel(const float* __restrict__ W, short8* __restrict__ pk) {
    __shared__ float tile[64][68];
    const int b2 = blockIdx.x;           // s*8 + w
    const int s = b2 >> 3, w = b2 & 7;
    const int t = s >> 3, c0 = (s & 7) << 6;
    const int tid = threadIdx.x;
    {
        int r = tid >> 2, c4 = (tid & 3) << 4;
        const float* src = W + (size_t)(t * 512 + c0 + r) * D_DIM + (w << 6) + c4;
#pragma unroll
        for (int j = 0; j < 4; ++j) {
            float4 v = *(const float4*)(src + 4 * j);
            tile[r][c4 + 4 * j + 0] = v.x;
            tile[r][c4 + 4 * j + 1] = v.y;
            tile[r][c4 + 4 * j + 2] = v.z;
            tile[r][c4 + 4 * j + 3] = v.w;
        }
    }
    __syncthreads();
    const int lane = tid & 63, f2 = tid >> 6;
#pragma unroll
    for (int ff = 0; ff < 2; ++ff) {
        int f = f2 * 2 + ff;
        int n = f >> 1, k32 = f & 1;
        short8 u;
#pragma unroll
        for (int e = 0; e < 8; ++e)
            u[e] = (short)f2b(tile[k32 * 32 + (lane >> 4) * 8 + e][n * 16 + (lane & 15)]);
        pk[((size_t)b2 * 8 + f) * 64 + lane] = u;
    }
}

// ---------------------------------------------------------------------------
// Fused windows-GEMM + bias + exact GELU + LayerNorm.
// Block: batch b, windows [n0, n0+64). 8 waves; wave w owns cols [64w, 64w+64).
// B: fragment-packed global -> registers, double-buffered (no LDS).
// A: fp32->bf16 reg-staged into double-buffered LDS, 2-phase pipeline.
// ---------------------------------------------------------------------------
__device__ __forceinline__ void load_b(const short8* __restrict__ pk, int s, int wid,
                                       int lane, short8 (&b)[4][2]) {
    const short8* base = pk + ((size_t)(s * 8 + wid) * 8) * 64 + lane;
#pragma unroll
    for (int n = 0; n < 4; ++n)
#pragma unroll
        for (int k32 = 0; k32 < 2; ++k32)
            b[n][k32] = base[(n * 2 + k32) * 64];
}

__global__ __launch_bounds__(THREADS, 2)
void fused_kernel(const float* __restrict__ x,
                  const short8* __restrict__ pk,
                  const float* __restrict__ bias,
                  const float* __restrict__ gamma,
                  const float* __restrict__ beta,
                  float* __restrict__ out)
{
    __shared__ __align__(16) unsigned short lsA[2][64 * 64];   // 2 x 8 KB
    __shared__ float redS[8][64];
    __shared__ float redQ[8][64];

    const int blk = blockIdx.x;
    const int b  = blk >> 3;
    const int n0 = (blk & 7) << 6;
    const int tid = threadIdx.x;
    const int lane = tid & 63;
    const int wid  = tid >> 6;
    const int r15 = lane & 15, hi = lane >> 4;
    const int ai = tid >> 3, ak8 = tid & 7;          // A-staging coords
    const int akb = ak8 ^ (ai & 7);                  // swizzled slot
    const float* xb = x + (size_t)b * S_LEN * D_DIM;

    f32x4 acc[4][4] = {};
    short8 bc[4][2], bn[4][2];

    // ---- prologue: stage A(s=0), load B(s=0) ----
    {
        int row = 8 * (n0 + ai) + 0;
        if (row > S_LEN - 1) row = S_LEN - 1;
        const float* src = xb + (size_t)row * D_DIM + 0 + ak8 * 8;
        float4 f0 = *(const float4*)src;
        float4 f1 = *(const float4*)(src + 4);
        short8 u;
        u[0] = (short)f2b(f0.x); u[1] = (short)f2b(f0.y);
        u[2] = (short)f2b(f0.z); u[3] = (short)f2b(f0.w);
        u[4] = (short)f2b(f1.x); u[5] = (short)f2b(f1.y);
        u[6] = (short)f2b(f1.z); u[7] = (short)f2b(f1.w);
        *(short8*)&lsA[0][ai * 64 + akb * 8] = u;
        load_b(pk, 0, wid, lane, bc);
    }
    __syncthreads();

    // ---- main loop: 128 K-steps, unrolled x2 for static dbuf indices ----
#define STEP(S, CUR, NXT, BCUR, BNXT)                                          \
    {                                                                          \
        const int sn = ((S) + 1) & 127;                                        \
        /* B prefetch (registers) */                                           \
        load_b(pk, sn, wid, lane, BNXT);                                       \
        /* A prefetch: issue loads now, convert+write after MFMA */            \
        const int tn = sn >> 3, c0n = (sn & 7) << 6;                           \
        int rown = 8 * (n0 + ai) + tn;                                         \
        if (rown > S_LEN - 1) rown = S_LEN - 1;                                \
        const float* asrc = xb + (size_t)rown * D_DIM + c0n + ak8 * 8;         \
        float4 f0 = *(const float4*)asrc;                                      \
        float4 f1 = *(const float4*)(asrc + 4);                                \
        /* A fragments from LDS (cur) */                                       \
        short8 afr[4][2];                                                      \
        _Pragma("unroll")                                                      \
        for (int m = 0; m < 4; ++m) {                                          \
            int row = 16 * m + r15;                                            \
            _Pragma("unroll")                                                  \
            for (int k32 = 0; k32 < 2; ++k32) {                                \
                int kb = (k32 * 4 + hi) ^ (row & 7);                           \
                afr[m][k32] = *(const short8*)&lsA[CUR][row * 64 + kb * 8];    \
            }                                                                  \
        }                                                                      \
        /* MFMA cluster */                                                     \
        _Pragma("unroll")                                                      \
        for (int k32 = 0; k32 < 2; ++k32)                                      \
            _Pragma("unroll")                                                  \
            for (int m = 0; m < 4; ++m)                                        \
                _Pragma("unroll")                                              \
                for (int n = 0; n < 4; ++n)                                    \
                    acc[m][n] = __builtin_amdgcn_mfma_f32_16x16x32_bf16(       \
                        afr[m][k32], BCUR[n][k32], acc[m][n], 0, 0, 0);        \
        /* A convert + ds_write into next buffer */                            \
        short8 u;                                                              \
        u[0] = (short)f2b(f0.x); u[1] = (short)f2b(f0.y);                      \
        u[2] = (short)f2b(f0.z); u[3] = (short)f2b(f0.w);                      \
        u[4] = (short)f2b(f1.x); u[5] = (short)f2b(f1.y);                      \
        u[6] = (short)f2b(f1.z); u[7] = (short)f2b(f1.w);                      \
        *(short8*)&lsA[NXT][ai * 64 + akb * 8] = u;                            \
        __syncthreads();                                                       \
    }

    for (int it = 0; it < 64; ++it) {
        STEP(it * 2,     0, 1, bc, bn)
        STEP(it * 2 + 1, 1, 0, bn, bc)
    }
#undef STEP

    // ---- epilogue: bias + exact GELU + LayerNorm ----
    float bias4[4], gam4[4], bet4[4];
#pragma unroll
    for (int n = 0; n < 4; ++n) {
        int d = (wid << 6) + 16 * n + r15;
        bias4[n] = bias[d]; gam4[n] = gamma[d]; bet4[n] = beta[d];
    }
    float sum_[4][4], sq_[4][4];   // [m][reg]
#pragma unroll
    for (int m = 0; m < 4; ++m)
#pragma unroll
        for (int r = 0; r < 4; ++r) { sum_[m][r] = 0.f; sq_[m][r] = 0.f; }
#pragma unroll
    for (int m = 0; m < 4; ++m)
#pragma unroll
        for (int n = 0; n < 4; ++n)
#pragma unroll
            for (int r = 0; r < 4; ++r) {
                float h = acc[m][n][r] + bias4[n];
                float g = 0.5f * h * (1.0f + erff(h * 0.70710678118654752f));
                acc[m][n][r] = g;
                sum_[m][r] += g;
                sq_[m][r]  += g * g;
            }
#pragma unroll
    for (int m = 0; m < 4; ++m)
#pragma unroll
        for (int r = 0; r < 4; ++r) {
            float sv = sum_[m][r], qv = sq_[m][r];
#pragma unroll
            for (int msk = 1; msk < 16; msk <<= 1) {
                sv += __shfl_xor(sv, msk, 64);
                qv += __shfl_xor(qv, msk, 64);
            }
            sum_[m][r] = sv; sq_[m][r] = qv;
        }
    if (r15 == 0) {
#pragma unroll
        for (int m = 0; m < 4; ++m)
#pragma unroll
            for (int r = 0; r < 4; ++r) {
                int row16 = 16 * m + hi * 4 + r;
                redS[wid][row16] = sum_[m][r];
                redQ[wid][row16] = sq_[m][r];
            }
    }
    __syncthreads();
#pragma unroll
    for (int m = 0; m < 4; ++m) {
#pragma unroll
        for (int r = 0; r < 4; ++r) {
            int row16 = 16 * m + hi * 4 + r;
            float sv = 0.f, qv = 0.f;
#pragma unroll
            for (int w = 0; w < 8; ++w) { sv += redS[w][row16]; qv += redQ[w][row16]; }
            float mu  = sv * (1.0f / 512.0f);
            float var = qv * (1.0f / 512.0f) - mu * mu;
            float inv = rsqrtf(var + 1e-5f);
            int win = n0 + row16;
            if (win < NWIN) {
                size_t obase = ((size_t)b * NWIN + win) * D_DIM;
#pragma unroll
                for (int n = 0; n < 4; ++n) {
                    int d = (wid << 6) + 16 * n + r15;
                    out[obase + d] = (acc[m][n][r] - mu) * inv * gam4[n] + bet4[n];
                }
            }
        }
    }
}

// Naive fallback (only if ws cannot hold the 8 MB packed W) — correct, slow.
__global__ void naive_kernel(const float* __restrict__ x, const float* __restrict__ W,
                             const float* __restrict__ bias, const float* __restrict__ gamma,
                             const float* __restrict__ beta, float* __restrict__ out) {
    __shared__ float hrow[D_DIM];
    __shared__ float red[2];
    const int b = blockIdx.x / NWIN, win = blockIdx.x % NWIN;
    const int d = threadIdx.x;
    float a = 0.f;
    for (int t = 0; t < 16; ++t) {
        const float* xr = x + ((size_t)b * S_LEN + 8 * win + t) * D_DIM;
        const float* wr = W + (size_t)t * D_DIM * D_DIM;
        for (int k = 0; k < D_DIM; ++k) a += xr[k] * wr[(size_t)k * D_DIM + d];
    }
    a += bias[d];
    a = 0.5f * a * (1.0f + erff(a * 0.70710678118654752f));
    hrow[d] = a;
    __syncthreads();
    if (d == 0) {
        float s = 0.f, q = 0.f;
        for (int k = 0; k < D_DIM; ++k) { s += hrow[k]; q += hrow[k] * hrow[k]; }
        float mu = s / D_DIM;
        red[0] = mu; red[1] = rsqrtf(q / D_DIM - mu * mu + 1e-5f);
    }
    __syncthreads();
    out[((size_t)b * NWIN + win) * D_DIM + d] = (a - red[0]) * red[1] * gamma[d] + beta[d];
}

extern "C" void kernel_launch(void* const* d_in, const int* in_sizes, int n_in,
                              void* d_out, int out_size, void* d_ws, size_t ws_size,
                              hipStream_t stream) {
    const float* x     = (const float*)d_in[0];
    const float* W     = (const float*)d_in[1];
    const float* bias  = (const float*)d_in[2];
    const float* gamma = (const float*)d_in[3];
    const float* beta  = (const float*)d_in[4];
    float* out = (float*)d_out;

    const size_t pk_bytes = (size_t)KDIM * D_DIM * sizeof(unsigned short);  // 8 MB
    if (ws_size >= pk_bytes) {
        short8* pk = (short8*)d_ws;
        wpack_kernel<<<1024, 256, 0, stream>>>(W, (short8*)pk);
        fused_kernel<<<256, THREADS, 0, stream>>>(x, pk, bias, gamma, beta, out);
    } else {
        naive_kernel<<<32 * NWIN, D_DIM, 0, stream>>>(x, W, bias, gamma, beta, out);
    }
}

// Round 3
// 195.992 us; speedup vs baseline: 1.3482x; 1.1136x over previous
//
#include <hip/hip_runtime.h>
#include <hip/hip_bf16.h>
#include <cstdint>

#define S_LEN 4096
#define D_DIM 512
#define NWIN  511
#define KDIM  8192
#define THREADS 512

typedef __attribute__((ext_vector_type(8))) short short8;
typedef __attribute__((ext_vector_type(4))) float f32x4;

__device__ __forceinline__ unsigned short f2b(float f) {
    union { float f; unsigned int u; } v; v.f = f;
    unsigned int r = v.u + 0x7FFFu + ((v.u >> 16) & 1u);
    return (unsigned short)(r >> 16);
}

// ---------------------------------------------------------------------------
// Pre-pass: pack W [8192][512] fp32 into bf16 MFMA-fragment order.
// For K-step s (t=s>>3, c0=(s&7)*64), wave w, frag f=(n*2+k32), lane l, elem e:
//   value = W[t*512 + c0 + k32*32 + (l>>4)*8 + e][64w + 16n + (l&15)]
//   at short8 slot ((s*8+w)*8 + f)*64 + l.
// ---------------------------------------------------------------------------
__global__ void wpack_kernel(const float* __restrict__ W, short8* __restrict__ pk) {
    __shared__ float tile[64][68];
    const int b2 = blockIdx.x;           // s*8 + w
    const int s = b2 >> 3, w = b2 & 7;
    const int t = s >> 3, c0 = (s & 7) << 6;
    const int tid = threadIdx.x;
    {
        int r = tid >> 2, c4 = (tid & 3) << 4;
        const float* src = W + (size_t)(t * 512 + c0 + r) * D_DIM + (w << 6) + c4;
#pragma unroll
        for (int j = 0; j < 4; ++j) {
            float4 v = *(const float4*)(src + 4 * j);
            tile[r][c4 + 4 * j + 0] = v.x;
            tile[r][c4 + 4 * j + 1] = v.y;
            tile[r][c4 + 4 * j + 2] = v.z;
            tile[r][c4 + 4 * j + 3] = v.w;
        }
    }
    __syncthreads();
    const int lane = tid & 63, f2 = tid >> 6;
#pragma unroll
    for (int ff = 0; ff < 2; ++ff) {
        int f = f2 * 2 + ff;
        int n = f >> 1, k32 = f & 1;
        short8 u;
#pragma unroll
        for (int e = 0; e < 8; ++e)
            u[e] = (short)f2b(tile[k32 * 32 + (lane >> 4) * 8 + e][n * 16 + (lane & 15)]);
        pk[((size_t)b2 * 8 + f) * 64 + lane] = u;
    }
}

__device__ __forceinline__ void load_b(const short8* __restrict__ pk, int s, int wid,
                                       int lane, short8 (&b)[4][2]) {
    const short8* base = pk + ((size_t)(s * 8 + wid) * 8) * 64 + lane;
#pragma unroll
    for (int n = 0; n < 4; ++n)
#pragma unroll
        for (int k32 = 0; k32 < 2; ++k32)
            b[n][k32] = base[(n * 2 + k32) * 64];
}

// ---------------------------------------------------------------------------
// Fused windows-GEMM + bias + exact GELU + LayerNorm.
// Block: batch b, windows [n0, n0+64). 8 waves; wave w owns cols [64w, 64w+64).
// B: fragment-packed global -> registers, double-buffered (no LDS).
// A: fp32->bf16 reg-staged into double-buffered LDS.
// Raw s_barrier (no vmcnt drain) keeps B prefetch in flight across steps (T4).
// ---------------------------------------------------------------------------
__global__ __launch_bounds__(THREADS, 2)
void fused_kernel(const float* __restrict__ x,
                  const short8* __restrict__ pk,
                  const float* __restrict__ bias,
                  const float* __restrict__ gamma,
                  const float* __restrict__ beta,
                  float* __restrict__ out)
{
    __shared__ __align__(16) unsigned short lsA[2][64 * 64];   // 2 x 8 KB
    __shared__ float redS[8][64];
    __shared__ float redQ[8][64];

    const int blk = blockIdx.x;
    const int b  = blk >> 3;
    const int n0 = (blk & 7) << 6;
    const int tid = threadIdx.x;
    const int lane = tid & 63;
    const int wid  = tid >> 6;
    const int r15 = lane & 15, hi = lane >> 4;
    const int ai = tid >> 3, ak8 = tid & 7;          // A-staging coords
    const int akb = ak8 ^ (ai & 7);                  // swizzled slot
    const float* xb = x + (size_t)b * S_LEN * D_DIM;

    f32x4 acc[4][4] = {};
    short8 bc[4][2], bn[4][2];

    // ---- prologue: stage A(s=0), load B(s=0) ----
    {
        int row = 8 * (n0 + ai) + 0;
        if (row > S_LEN - 1) row = S_LEN - 1;
        const float* src = xb + (size_t)row * D_DIM + 0 + ak8 * 8;
        float4 f0 = *(const float4*)src;
        float4 f1 = *(const float4*)(src + 4);
        short8 u;
        u[0] = (short)f2b(f0.x); u[1] = (short)f2b(f0.y);
        u[2] = (short)f2b(f0.z); u[3] = (short)f2b(f0.w);
        u[4] = (short)f2b(f1.x); u[5] = (short)f2b(f1.y);
        u[6] = (short)f2b(f1.z); u[7] = (short)f2b(f1.w);
        *(short8*)&lsA[0][ai * 64 + akb * 8] = u;
        load_b(pk, 0, wid, lane, bc);
    }
    __syncthreads();

    // ---- main loop: 128 K-steps, unrolled x2 for static dbuf indices ----
    // Per step: issue A loads (2 vmem) FIRST, then B loads (8 vmem), so the
    // ds_write's wait is counted vmcnt(8) and B stays in flight across the
    // raw barrier (no vmcnt drain — only lgkmcnt(0) for ds_write visibility).
#define STEP(S, CUR, NXT, BCUR, BNXT)                                          \
    {                                                                          \
        const int sn = ((S) + 1) & 127;                                        \
        /* A prefetch: issue loads first */                                    \
        const int tn = sn >> 3, c0n = (sn & 7) << 6;                           \
        int rown = 8 * (n0 + ai) + tn;                                         \
        if (rown > S_LEN - 1) rown = S_LEN - 1;                                \
        const float* asrc = xb + (size_t)rown * D_DIM + c0n + ak8 * 8;         \
        float4 f0 = *(const float4*)asrc;                                      \
        float4 f1 = *(const float4*)(asrc + 4);                                \
        /* B prefetch (registers), issued after A */                           \
        load_b(pk, sn, wid, lane, BNXT);                                       \
        /* A fragments from LDS (cur) */                                       \
        short8 afr[4][2];                                                      \
        _Pragma("unroll")                                                      \
        for (int m = 0; m < 4; ++m) {                                          \
            int row = 16 * m + r15;                                            \
            _Pragma("unroll")                                                  \
            for (int k32 = 0; k32 < 2; ++k32) {                                \
                int kb = (k32 * 4 + hi) ^ (row & 7);                           \
                afr[m][k32] = *(const short8*)&lsA[CUR][row * 64 + kb * 8];    \
            }                                                                  \
        }                                                                      \
        /* MFMA cluster (waits: lgkm for afr, counted vmcnt for B(S)) */       \
        _Pragma("unroll")                                                      \
        for (int k32 = 0; k32 < 2; ++k32)                                      \
            _Pragma("unroll")                                                  \
            for (int m = 0; m < 4; ++m)                                        \
                _Pragma("unroll")                                              \
                for (int n = 0; n < 4; ++n)                                    \
                    acc[m][n] = __builtin_amdgcn_mfma_f32_16x16x32_bf16(       \
                        afr[m][k32], BCUR[n][k32], acc[m][n], 0, 0, 0);        \
        /* A convert + ds_write into next buffer (waits counted vmcnt(8)) */   \
        short8 u;                                                              \
        u[0] = (short)f2b(f0.x); u[1] = (short)f2b(f0.y);                      \
        u[2] = (short)f2b(f0.z); u[3] = (short)f2b(f0.w);                      \
        u[4] = (short)f2b(f1.x); u[5] = (short)f2b(f1.y);                      \
        u[6] = (short)f2b(f1.z); u[7] = (short)f2b(f1.w);                      \
        *(short8*)&lsA[NXT][ai * 64 + akb * 8] = u;                            \
        asm volatile("s_waitcnt lgkmcnt(0)" ::: "memory");                     \
        __builtin_amdgcn_s_barrier();                                          \
        __builtin_amdgcn_sched_barrier(0);                                     \
    }

    for (int it = 0; it < 64; ++it) {
        STEP(it * 2,     0, 1, bc, bn)
        STEP(it * 2 + 1, 1, 0, bn, bc)
    }
#undef STEP

    // ---- epilogue: bias + exact GELU + LayerNorm ----
    float bias4[4], gam4[4], bet4[4];
#pragma unroll
    for (int n = 0; n < 4; ++n) {
        int d = (wid << 6) + 16 * n + r15;
        bias4[n] = bias[d]; gam4[n] = gamma[d]; bet4[n] = beta[d];
    }
    float sum_[4][4], sq_[4][4];   // [m][reg]
#pragma unroll
    for (int m = 0; m < 4; ++m)
#pragma unroll
        for (int r = 0; r < 4; ++r) { sum_[m][r] = 0.f; sq_[m][r] = 0.f; }
#pragma unroll
    for (int m = 0; m < 4; ++m)
#pragma unroll
        for (int n = 0; n < 4; ++n)
#pragma unroll
            for (int r = 0; r < 4; ++r) {
                float h = acc[m][n][r] + bias4[n];
                float g = 0.5f * h * (1.0f + erff(h * 0.70710678118654752f));
                acc[m][n][r] = g;
                sum_[m][r] += g;
                sq_[m][r]  += g * g;
            }
#pragma unroll
    for (int m = 0; m < 4; ++m)
#pragma unroll
        for (int r = 0; r < 4; ++r) {
            float sv = sum_[m][r], qv = sq_[m][r];
#pragma unroll
            for (int msk = 1; msk < 16; msk <<= 1) {
                sv += __shfl_xor(sv, msk, 64);
                qv += __shfl_xor(qv, msk, 64);
            }
            sum_[m][r] = sv; sq_[m][r] = qv;
        }
    if (r15 == 0) {
#pragma unroll
        for (int m = 0; m < 4; ++m)
#pragma unroll
            for (int r = 0; r < 4; ++r) {
                int row16 = 16 * m + hi * 4 + r;
                redS[wid][row16] = sum_[m][r];
                redQ[wid][row16] = sq_[m][r];
            }
    }
    __syncthreads();
#pragma unroll
    for (int m = 0; m < 4; ++m) {
#pragma unroll
        for (int r = 0; r < 4; ++r) {
            int row16 = 16 * m + hi * 4 + r;
            float sv = 0.f, qv = 0.f;
#pragma unroll
            for (int w = 0; w < 8; ++w) { sv += redS[w][row16]; qv += redQ[w][row16]; }
            float mu  = sv * (1.0f / 512.0f);
            float var = qv * (1.0f / 512.0f) - mu * mu;
            float inv = rsqrtf(var + 1e-5f);
            int win = n0 + row16;
            if (win < NWIN) {
                size_t obase = ((size_t)b * NWIN + win) * D_DIM;
#pragma unroll
                for (int n = 0; n < 4; ++n) {
                    int d = (wid << 6) + 16 * n + r15;
                    out[obase + d] = (acc[m][n][r] - mu) * inv * gam4[n] + bet4[n];
                }
            }
        }
    }
}

// Naive fallback (only if ws cannot hold the 8 MB packed W) — correct, slow.
__global__ void naive_kernel(const float* __restrict__ x, const float* __restrict__ W,
                             const float* __restrict__ bias, const float* __restrict__ gamma,
                             const float* __restrict__ beta, float* __restrict__ out) {
    __shared__ float hrow[D_DIM];
    __shared__ float red[2];
    const int b = blockIdx.x / NWIN, win = blockIdx.x % NWIN;
    const int d = threadIdx.x;
    float a = 0.f;
    for (int t = 0; t < 16; ++t) {
        const float* xr = x + ((size_t)b * S_LEN + 8 * win + t) * D_DIM;
        const float* wr = W + (size_t)t * D_DIM * D_DIM;
        for (int k = 0; k < D_DIM; ++k) a += xr[k] * wr[(size_t)k * D_DIM + d];
    }
    a += bias[d];
    a = 0.5f * a * (1.0f + erff(a * 0.70710678118654752f));
    hrow[d] = a;
    __syncthreads();
    if (d == 0) {
        float s = 0.f, q = 0.f;
        for (int k = 0; k < D_DIM; ++k) { s += hrow[k]; q += hrow[k] * hrow[k]; }
        float mu = s / D_DIM;
        red[0] = mu; red[1] = rsqrtf(q / D_DIM - mu * mu + 1e-5f);
    }
    __syncthreads();
    out[((size_t)b * NWIN + win) * D_DIM + d] = (a - red[0]) * red[1] * gamma[d] + beta[d];
}

extern "C" void kernel_launch(void* const* d_in, const int* in_sizes, int n_in,
                              void* d_out, int out_size, void* d_ws, size_t ws_size,
                              hipStream_t stream) {
    const float* x     = (const float*)d_in[0];
    const float* W     = (const float*)d_in[1];
    const float* bias  = (const float*)d_in[2];
    const float* gamma = (const float*)d_in[3];
    const float* beta  = (const float*)d_in[4];
    float* out = (float*)d_out;

    const size_t pk_bytes = (size_t)KDIM * D_DIM * sizeof(unsigned short);  // 8 MB
    if (ws_size >= pk_bytes) {
        short8* pk = (short8*)d_ws;
        wpack_kernel<<<1024, 256, 0, stream>>>(W, (short8*)pk);
        fused_kernel<<<256, THREADS, 0, stream>>>(x, pk, bias, gamma, beta, out);
    } else {
        naive_kernel<<<32 * NWIN, D_DIM, 0, stream>>>(x, W, bias, gamma, beta, out);
    }
}